// Round 9
// baseline (254.037 us; speedup 1.0000x reference)
//
#include <hip/hip_runtime.h>
#include <hip/hip_bf16.h>
#include <cstdint>
#include <cstddef>

#define T_DIM 1024
#define S_DIM 1024
#define N_HEADS 32
#define D_HEAD 128

typedef __attribute__((ext_vector_type(8))) short short8;
typedef __attribute__((ext_vector_type(4))) float floatx4;

__device__ inline int pack_bf16(float a, float b) {
    __hip_bfloat162 h = __float22bfloat162_rn(make_float2(a, b));
    int r; __builtin_memcpy(&r, &h, 4); return r;
}
__device__ inline ushort f2b(float x) {
    __hip_bfloat16 h = __float2bfloat16(x);
    ushort u; __builtin_memcpy(&u, &h, 2); return u;
}
__device__ inline float b2f(ushort u) {
    unsigned int v = ((unsigned int)u) << 16;
    float f; __builtin_memcpy(&f, &v, 4); return f;
}

// ---------------------------------------------------------------------------
// prep: fused mat4 + tobf16 + vt (bodies verbatim from the verified kernels).
// 1D grid 6656 blocks: [0,4096) mat4, [4096,6144) tobf16, [6144,6656) vt.
// ---------------------------------------------------------------------------
__global__ __launch_bounds__(256) void prep(
        const float* __restrict__ Q, const float* __restrict__ K,
        const float* __restrict__ V,
        const float* __restrict__ sw_pre,  const float* __restrict__ qw1_pre,
        const float* __restrict__ qw2_pre, const float* __restrict__ qdd_pre,
        const float* __restrict__ kw1_pre, const float* __restrict__ kw2_pre,
        const float* __restrict__ kdd_pre,
        const float* __restrict__ sw_post,  const float* __restrict__ qw1_post,
        const float* __restrict__ qw2_post, const float* __restrict__ qdd_post,
        const float* __restrict__ kw1_post, const float* __restrict__ kw2_post,
        const float* __restrict__ kdd_post,
        ushort* __restrict__ mats, ushort* __restrict__ Qb,
        ushort* __restrict__ Kb, ushort* __restrict__ Vt) {
    __shared__ float lds[128 * 65];
    const int bid = blockIdx.x;
    const int tid = threadIdx.x;

    if (bid < 4096) {
        // ---- mat4: fam = bid&3 (XCD spread), t = bid>>2
        const int fam = bid & 3;
        const int t   = bid >> 2;
        const float *sw, *w1, *w2, *dd;
        float idadd;
        switch (fam) {
            case 0:  sw = sw_pre;  w1 = qw1_pre;  w2 = qw2_pre;  dd = qdd_pre;  idadd = 1.0f; break;
            case 1:  sw = nullptr; w1 = kw1_pre;  w2 = kw2_pre;  dd = kdd_pre;  idadd = 0.0f; break;
            case 2:  sw = sw_post; w1 = qw1_post; w2 = qw2_post; dd = qdd_post; idadd = 1.0f; break;
            default: sw = nullptr; w1 = kw1_post; w2 = kw2_post; dd = kdd_post; idadd = 0.0f; break;
        }
        ushort* out = mats + (size_t)fam * 1024 * 1024;
        const int m = tid >> 3;
        const int n0 = (tid & 7) * 4;
        const float w2m0 = w2[t * 64 + m];
        const float w2m1 = w2[t * 64 + 32 + m];
        const float ddm  = dd[t * 32 + m];
        float v[4];
        #pragma unroll
        for (int j = 0; j < 4; ++j) {
            int n = n0 + j;
            float r = w1[t * 64 + n] * w2m0 + w1[t * 64 + 32 + n] * w2m1;
            if (sw) r += sw[n * 32 + m];
            if (n == m) r += idadd + ddm;
            v[j] = r;
        }
        int2 st = make_int2(pack_bf16(v[0], v[1]), pack_bf16(v[2], v[3]));
        *(int2*)&out[(size_t)t * 1024 + m * 32 + n0] = st;
    } else if (bid < 6144) {
        // ---- tobf16
        const size_t gid = (size_t)(bid - 4096) * 256 + tid;   // 0..524287
        #pragma unroll
        for (int j = 0; j < 2; ++j) {
            size_t i = gid + (size_t)j * 524288;               // float4 idx
            float4 q = ((const float4*)Q)[i];
            int2 qp; qp.x = pack_bf16(q.x, q.y); qp.y = pack_bf16(q.z, q.w);
            ((int2*)Qb)[i] = qp;
            float4 k = ((const float4*)K)[i];
            int2 kp; kp.x = pack_bf16(k.x, k.y); kp.y = pack_bf16(k.z, k.w);
            ((int2*)Kb)[i] = kp;
        }
    } else {
        // ---- vt: Vt[n][d][s] <- V[n][s][d]
        const int vb = bid - 6144;            // 0..511
        const int s0 = (vb & 15) * 64;
        const int n  = vb >> 4;
        const float* Vn = V + ((size_t)n * S_DIM + s0) * D_HEAD;
        #pragma unroll
        for (int it = 0; it < 8; ++it) {
            int idx = tid + it * 256;
            int d4 = idx & 31, s = idx >> 5;
            float4 v = *(const float4*)(Vn + (size_t)s * D_HEAD + d4 * 4);
            lds[(d4 * 4 + 0) * 65 + s] = v.x;
            lds[(d4 * 4 + 1) * 65 + s] = v.y;
            lds[(d4 * 4 + 2) * 65 + s] = v.z;
            lds[(d4 * 4 + 3) * 65 + s] = v.w;
        }
        __syncthreads();
        ushort* Vtn = Vt + (size_t)n * D_HEAD * S_DIM;
        #pragma unroll
        for (int it = 0; it < 4; ++it) {
            int idx = tid + it * 256;
            int sg = idx & 7, d = idx >> 3;
            const float* src = &lds[d * 65 + sg * 8];
            int4 o;
            o.x = pack_bf16(src[0], src[1]);
            o.y = pack_bf16(src[2], src[3]);
            o.z = pack_bf16(src[4], src[5]);
            o.w = pack_bf16(src[6], src[7]);
            *(int4*)&Vtn[(size_t)d * S_DIM + s0 + sg * 8] = o;
        }
    }
}

// ---------------------------------------------------------------------------
// qk3: logits via MFMA, 64t x 128s per block (two K-tiles share one staged
// Q-tile). Staging/fragment/swizzle layout byte-identical to the verified
// qk2; Kt1 path is block-uniform. 48 KB LDS -> 3 blocks/CU (was 2).
// Active blocks 2304 (was 4352). XCD remap: pair % 8 == xcd, sp fastest.
// ---------------------------------------------------------------------------
__global__ __launch_bounds__(256, 3) void qk3(const ushort* __restrict__ Qb,
                                              const ushort* __restrict__ Kb,
                                              ushort* __restrict__ Lb) {
    const int bid  = blockIdx.x;           // 0..4095
    const int xcd  = bid & 7;
    const int i    = bid >> 3;             // 0..511
    const int sp   = i & 7;
    const int pair = (i >> 3) * 8 + xcd;   // 0..511 bijective
    const int n    = pair >> 4;
    const int tt   = pair & 15;
    const int st0  = sp * 2;
    if (st0 > tt) return;
    const bool two = (st0 + 1 <= tt);      // block-uniform

    __shared__ int Qt[64 * 64];
    __shared__ int Kt0[64 * 64];
    __shared__ int Kt1[64 * 64];

    const int tid = threadIdx.x;
    const int wv = tid >> 6, ln = tid & 63;
    const int frow = ln & 15, quad = ln >> 4;

    const ushort* Qn  = Qb + ((size_t)n * T_DIM + (size_t)tt * 64) * D_HEAD;
    const ushort* Kn0 = Kb + ((size_t)n * S_DIM + (size_t)st0 * 64) * D_HEAD;
    const ushort* Kn1 = Kn0 + (size_t)64 * D_HEAD;

    #pragma unroll
    for (int rep = 0; rep < 4; ++rep) {
        int idx = tid + rep * 256;          // 0..1023
        int row = idx >> 4;
        int c   = idx & 15;                 // 16 B chunk = 8 bf16
        int dst = row * 64 + (c >> 2) * 16 + (((c & 3) * 4) ^ (4 * (row & 3)));
        *(uint4*)&Qt[dst]  = *(const uint4*)(Qn  + (size_t)row * D_HEAD + c * 8);
        *(uint4*)&Kt0[dst] = *(const uint4*)(Kn0 + (size_t)row * D_HEAD + c * 8);
        if (two)
            *(uint4*)&Kt1[dst] = *(const uint4*)(Kn1 + (size_t)row * D_HEAD + c * 8);
    }
    __syncthreads();

    const int swz = 4 * (frow & 3);
    floatx4 acc0[4] = {};
    floatx4 acc1[4] = {};
    #pragma unroll
    for (int kb = 0; kb < 4; ++kb) {
        const short8 af = *(const short8*)&Qt[(wv * 16 + frow) * 64 + kb * 16 + ((quad * 4) ^ swz)];
        #pragma unroll
        for (int si = 0; si < 4; ++si) {
            const int off = (si * 16 + frow) * 64 + kb * 16 + ((quad * 4) ^ swz);
            const short8 bf0 = *(const short8*)&Kt0[off];
            acc0[si] = __builtin_amdgcn_mfma_f32_16x16x32_bf16(af, bf0, acc0[si], 0, 0, 0);
            if (two) {
                const short8 bf1 = *(const short8*)&Kt1[off];
                acc1[si] = __builtin_amdgcn_mfma_f32_16x16x32_bf16(af, bf1, acc1[si], 0, 0, 0);
            }
        }
    }
    __syncthreads();                    // all LDS dead -> reuse as output tiles

    ushort* Ot0 = (ushort*)Qt;          // [64][72] bf16, 9 KB
    ushort* Ot1 = (ushort*)Kt0;
    #pragma unroll
    for (int si = 0; si < 4; ++si)
        #pragma unroll
        for (int r = 0; r < 4; ++r) {
            Ot0[(wv * 16 + quad * 4 + r) * 72 + si * 16 + frow] = f2b(acc0[si][r]);
            if (two)
                Ot1[(wv * 16 + quad * 4 + r) * 72 + si * 16 + frow] = f2b(acc1[si][r]);
        }
    __syncthreads();

    #pragma unroll
    for (int it = 0; it < 2; ++it) {
        int idx = tid + it * 256;
        int row = idx >> 3, col = idx & 7;
        ushort* dst = &Lb[((size_t)n * T_DIM + tt * 64 + row) * S_DIM + st0 * 64 + col * 8];
        *(int4*)dst = *(const int4*)&Ot0[row * 72 + col * 8];
        if (two)
            *(int4*)(dst + 64) = *(const int4*)&Ot1[row * 72 + col * 8];
    }
}

// ---------------------------------------------------------------------------
// proj6: fused cross-head projection + XCD remap. SM=false emits per-(row,
// 16s-tile) LSE partials from registers; SM=true applies softmax from
// stats2[t][n] during staging. (unchanged from round 8)
// ---------------------------------------------------------------------------
template<bool SM>
__global__ __launch_bounds__(256, 4) void proj6(ushort* __restrict__ Lb,
                                                const ushort* __restrict__ Cmat,
                                                const ushort* __restrict__ Kmat,
                                                const float2* __restrict__ stats2,
                                                float2* __restrict__ pstat) {
    const int bid = blockIdx.y * 64 + blockIdx.x;
    const int xcd = bid & 7;
    const int idx = bid >> 3;                 // 0..511
    const int ty  = ((idx >> 6) << 3) + xcd;  // ty % 8 == xcd
    const int sx  = idx & 63;

    const int s0 = sx * 16;
    const int t0 = ty * 16;
    if (s0 > t0 + 15) return;

    __shared__ __align__(16) ushort Xs[16 * 648];   // 20736 B  [t][s:40][m]
    __shared__ __align__(16) float  Kp[16 * 260];   // 16640 B  [t][s:16][n]

    const int tid = threadIdx.x;
    const int wv = tid >> 6, ln = tid & 63;
    const int frow = ln & 15, quad = ln >> 4;

    #pragma unroll
    for (int it = 0; it < 4; ++it) {
        int slot = tid + it * 256;
        int c    = slot & 1;
        int row  = slot >> 1;
        int nn   = row >> 4, tl = row & 15;
        uint4 ld = *(const uint4*)(Lb + ((size_t)nn * T_DIM + t0 + tl) * S_DIM + s0 + c * 8);
        ushort u[8];
        u[0] = (ushort)(ld.x & 0xffff);  u[1] = (ushort)(ld.x >> 16);
        u[2] = (ushort)(ld.y & 0xffff);  u[3] = (ushort)(ld.y >> 16);
        u[4] = (ushort)(ld.z & 0xffff);  u[5] = (ushort)(ld.z >> 16);
        u[6] = (ushort)(ld.w & 0xffff);  u[7] = (ushort)(ld.w >> 16);
        if (SM) {
            const float2 ms = stats2[(t0 + tl) * 32 + nn];
            const int tG = t0 + tl, sbase = s0 + c * 8;
            #pragma unroll
            for (int j = 0; j < 8; ++j) {
                float x = (sbase + j <= tG) ? __expf(b2f(u[j]) - ms.x) * ms.y : 0.0f;
                u[j] = f2b(x);
            }
        }
        ushort* xp = &Xs[tl * 648 + (c * 8) * 40 + nn];
        #pragma unroll
        for (int j = 0; j < 8; ++j) xp[j * 40] = u[j];
    }
    __syncthreads();

    #pragma unroll
    for (int mh = 0; mh < 2; ++mh) {
        #pragma unroll
        for (int k = 0; k < 4; ++k) {
            const int sl = wv * 4 + k;
            const short8 af = *(const short8*)(Kmat + (size_t)(s0 + sl) * 1024 + (mh * 16 + frow) * 32 + quad * 8);
            const short8 bf = *(const short8*)&Xs[frow * 648 + sl * 40 + quad * 8];
            floatx4 z = {0.f, 0.f, 0.f, 0.f};
            floatx4 d = __builtin_amdgcn_mfma_f32_16x16x32_bf16(af, bf, z, 0, 0, 0);
            *(floatx4*)&Kp[frow * 260 + sl * 16 + quad * 4] = d;
        }
        __syncthreads();

        #pragma unroll
        for (int i = 0; i < 4; ++i) {
            const int tl = wv * 4 + i;
            const int tg = t0 + tl;
            const short8 bf = *(const short8*)(Cmat + (size_t)tg * 1024 + (mh * 16 + frow) * 32 + quad * 8);
            const short8 af = *(const short8*)&Xs[tl * 648 + frow * 40 + quad * 8];
            floatx4 z = {0.f, 0.f, 0.f, 0.f};
            floatx4 d = __builtin_amdgcn_mfma_f32_16x16x32_bf16(af, bf, z, 0, 0, 0);
            float v[4];
            float lm = -INFINITY, lsum = 0.0f;
            #pragma unroll
            for (int r = 0; r < 4; ++r) {
                const int sl = quad * 4 + r;
                float val = d[r] + Kp[tl * 260 + sl * 16 + frow];
                const bool ok = (s0 + sl <= tg);
                v[r] = ok ? val : 0.0f;
                if (!SM) lm = fmaxf(lm, ok ? val : -INFINITY);
            }
            if (!SM) {
                #pragma unroll
                for (int r = 0; r < 4; ++r) {
                    const int sl = quad * 4 + r;
                    if (s0 + sl <= tg) lsum += __expf(v[r] - lm);
                }
                #pragma unroll
                for (int off = 16; off <= 32; off <<= 1) {
                    float om = __shfl_xor(lm, off);
                    float os = __shfl_xor(lsum, off);
                    float nm = fmaxf(lm, om);
                    float a = (lm > -1e37f) ? lsum * __expf(lm - nm) : 0.0f;
                    float b = (om > -1e37f) ? os   * __expf(om - nm) : 0.0f;
                    lm = nm; lsum = a + b;
                }
                if (quad == 0)
                    pstat[((size_t)tg * 64 + sx) * 32 + mh * 16 + frow] = make_float2(lm, lsum);
            }
            uint2 stv;
            stv.x = (unsigned)pack_bf16(v[0], v[1]);
            stv.y = (unsigned)pack_bf16(v[2], v[3]);
            *(uint2*)&Lb[((size_t)(mh * 16 + frow) * T_DIM + tg) * S_DIM + s0 + quad * 4] = stv;
        }
        __syncthreads();
    }
}

// ---------------------------------------------------------------------------
// statreduce: one block per t; merge LSE partials -> stats2[t][n]. (unchanged)
// ---------------------------------------------------------------------------
__global__ __launch_bounds__(256) void statreduce(const float2* __restrict__ pstat,
                                                  float2* __restrict__ stats2) {
    const int t = blockIdx.x;
    const int ty = t >> 4;
    const int total = (ty + 1) * 32;
    __shared__ float sm[32][65];
    __shared__ float ss[32][65];

    const int tid = threadIdx.x;
    for (int base = 0; base < total; base += 256) {
        int idx = base + tid;
        if (idx < total) {
            float2 p = pstat[(size_t)t * 2048 + idx];   // [t][sx][n]
            sm[idx & 31][idx >> 5] = p.x;
            ss[idx & 31][idx >> 5] = p.y;
        }
    }
    __syncthreads();

    const int n = tid >> 3, j = tid & 7;
    float m = -INFINITY, s = 0.0f;
    for (int sx = j; sx <= ty; sx += 8) {
        float om = sm[n][sx], os = ss[n][sx];
        float nm = fmaxf(m, om);
        float a = (m  > -1e37f) ? s  * __expf(m  - nm) : 0.0f;
        float b = (om > -1e37f) ? os * __expf(om - nm) : 0.0f;
        m = nm; s = a + b;
    }
    #pragma unroll
    for (int off = 1; off < 8; off <<= 1) {
        float om = __shfl_xor(m, off);
        float os = __shfl_xor(s, off);
        float nm = fmaxf(m, om);
        float a = (m  > -1e37f) ? s  * __expf(m  - nm) : 0.0f;
        float b = (om > -1e37f) ? os * __expf(om - nm) : 0.0f;
        m = nm; s = a + b;
    }
    if (j == 0) stats2[t * 32 + n] = make_float2(m, 1.0f / s);
}

// ---------------------------------------------------------------------------
// av4: O = P V via MFMA with B-fragment reuse. (unchanged)
// ---------------------------------------------------------------------------
__global__ __launch_bounds__(256, 3) void av4(const ushort* __restrict__ P,
                                              const ushort* __restrict__ Vt,
                                              float* __restrict__ O) {
    const int tid = threadIdx.x;
    const int wv = tid >> 6, ln = tid & 63;
    const int frow = ln & 15, quad = ln >> 4;
    const int n  = blockIdx.x;
    const int tt = 31 - blockIdx.y;      // big tiles first
    const int t0 = tt * 32;

    __shared__ ushort red[4][32][136];   // 34816 B bf16 partials

    const ushort* Pn  = P  + ((size_t)n * T_DIM + t0) * S_DIM;
    const ushort* Vtn = Vt + (size_t)n * D_HEAD * S_DIM;

    const int nsteps  = tt + 1;
    const int nclean0 = t0 >> 5;
    const int nclean1 = (t0 + 16) >> 5;

    floatx4 acc[2][8] = {};
    for (int sb = wv; sb < nsteps; sb += 4) {
        const int scol = sb * 32 + quad * 8;
        short8 a0 = *(const short8*)(Pn + (size_t)frow * S_DIM + scol);
        short8 a1 = *(const short8*)(Pn + (size_t)(16 + frow) * S_DIM + scol);
        if (sb >= nclean0) {
            const int tg = t0 + frow;
            #pragma unroll
            for (int j = 0; j < 8; ++j)
                if (scol + j > tg) a0[j] = 0;
        }
        if (sb >= nclean1) {
            const int tg = t0 + 16 + frow;
            #pragma unroll
            for (int j = 0; j < 8; ++j)
                if (scol + j > tg) a1[j] = 0;
        }
        #pragma unroll
        for (int dc = 0; dc < 8; ++dc) {
            const short8 b = *(const short8*)(Vtn + (size_t)(dc * 16 + frow) * S_DIM + sb * 32 + quad * 8);
            acc[0][dc] = __builtin_amdgcn_mfma_f32_16x16x32_bf16(a0, b, acc[0][dc], 0, 0, 0);
            acc[1][dc] = __builtin_amdgcn_mfma_f32_16x16x32_bf16(a1, b, acc[1][dc], 0, 0, 0);
        }
    }

    #pragma unroll
    for (int tq = 0; tq < 2; ++tq)
        #pragma unroll
        for (int dc = 0; dc < 8; ++dc)
            #pragma unroll
            for (int r = 0; r < 4; ++r)
                red[wv][tq * 16 + quad * 4 + r][dc * 16 + frow] = f2b(acc[tq][dc][r]);
    __syncthreads();

    #pragma unroll
    for (int it = 0; it < 4; ++it) {
        int idx = tid + it * 256;
        int d4 = idx & 31, tr = idx >> 5;     // tr 0..31
        float4 v;
        v.x = b2f(red[0][tr][d4 * 4 + 0]) + b2f(red[1][tr][d4 * 4 + 0]) + b2f(red[2][tr][d4 * 4 + 0]) + b2f(red[3][tr][d4 * 4 + 0]);
        v.y = b2f(red[0][tr][d4 * 4 + 1]) + b2f(red[1][tr][d4 * 4 + 1]) + b2f(red[2][tr][d4 * 4 + 1]) + b2f(red[3][tr][d4 * 4 + 1]);
        v.z = b2f(red[0][tr][d4 * 4 + 2]) + b2f(red[1][tr][d4 * 4 + 2]) + b2f(red[2][tr][d4 * 4 + 2]) + b2f(red[3][tr][d4 * 4 + 2]);
        v.w = b2f(red[0][tr][d4 * 4 + 3]) + b2f(red[1][tr][d4 * 4 + 3]) + b2f(red[2][tr][d4 * 4 + 3]) + b2f(red[3][tr][d4 * 4 + 3]);
        *(float4*)&O[((size_t)n * T_DIM + t0 + tr) * D_HEAD + d4 * 4] = v;
    }
}

// ---------------------------------------------------------------------------
extern "C" void kernel_launch(void* const* d_in, const int* in_sizes, int n_in,
                              void* d_out, int out_size, void* d_ws, size_t ws_size,
                              hipStream_t stream) {
    const float* Q    = (const float*)d_in[0];
    const float* K    = (const float*)d_in[1];
    const float* V    = (const float*)d_in[2];
    const float* sw_pre  = (const float*)d_in[4];
    const float* qw1_pre = (const float*)d_in[5];
    const float* qw2_pre = (const float*)d_in[6];
    const float* kw1_pre = (const float*)d_in[7];
    const float* kw2_pre = (const float*)d_in[8];
    const float* qdd_pre = (const float*)d_in[9];
    const float* kdd_pre = (const float*)d_in[10];
    const float* sw_post  = (const float*)d_in[11];
    const float* qw1_post = (const float*)d_in[12];
    const float* qw2_post = (const float*)d_in[13];
    const float* kw1_post = (const float*)d_in[14];
    const float* kw2_post = (const float*)d_in[15];
    const float* qdd_post = (const float*)d_in[16];
    const float* kdd_post = (const float*)d_in[17];

    // ws layout: Lb 64 MB | Vt 8 MB | Qb 8 MB | Kb 8 MB | pstat 16 MB (=104 MB)
    ushort* Lb = (ushort*)d_ws;
    ushort* Vt = (ushort*)((char*)d_ws + (size_t)64 * 1024 * 1024);
    ushort* Qb = (ushort*)((char*)d_ws + (size_t)72 * 1024 * 1024);
    ushort* Kb = (ushort*)((char*)d_ws + (size_t)80 * 1024 * 1024);
    float2* pstat = (float2*)((char*)d_ws + (size_t)96 * 1024 * 1024);
    float*  O  = (float*)d_out;

    // d_out scratch (16 MB): mats in first 8 MB, stats2 after.
    // Both fully consumed before av4 overwrites d_out.
    ushort* mats  = (ushort*)d_out;
    ushort* Cpre  = mats + 0 * 1024 * 1024;
    ushort* Kpre  = mats + 1 * 1024 * 1024;
    ushort* Cpost = mats + 2 * 1024 * 1024;
    ushort* Kpost = mats + 3 * 1024 * 1024;
    float2* stats2 = (float2*)((char*)d_out + (size_t)8 * 1024 * 1024);

    prep<<<dim3(6656), 256, 0, stream>>>(
        Q, K, V,
        sw_pre, qw1_pre, qw2_pre, qdd_pre, kw1_pre, kw2_pre, kdd_pre,
        sw_post, qw1_post, qw2_post, qdd_post, kw1_post, kw2_post, kdd_post,
        mats, Qb, Kb, Vt);

    qk3<<<dim3(4096), 256, 0, stream>>>(Qb, Kb, Lb);
    proj6<false><<<dim3(64, 64), 256, 0, stream>>>(Lb, Cpre, Kpre, nullptr, pstat);
    statreduce<<<dim3(1024), 256, 0, stream>>>(pstat, stats2);
    proj6<true><<<dim3(64, 64), 256, 0, stream>>>(Lb, Cpost, Kpost, stats2, nullptr);
    av4<<<dim3(32, 32), 256, 0, stream>>>(Lb, Vt, O);
}